// Round 5
// baseline (355.663 us; speedup 1.0000x reference)
//
#include <hip/hip_runtime.h>
#include <stdint.h>
#include <math.h>

#define FDIM 128
#define KDIM 384
#define NROWS 26112   // 512 hop0 rows + 25600 hop1 rows

struct Cols { int o25[25]; int i25[25]; int o10[10]; int i10[10]; };
struct ColsBoth { Cols c[2]; };

// ---------------- host-side JAX threefry (partitionable=True) ----------------
static inline uint32_t rotl32(uint32_t x, uint32_t r){ return (x<<r)|(x>>(32u-r)); }

static void tf2x32(uint32_t k0, uint32_t k1, uint32_t c0, uint32_t c1,
                   uint32_t& o0, uint32_t& o1){
  const uint32_t ra[4] = {13u,15u,26u,6u};
  const uint32_t rb[4] = {17u,29u,16u,24u};
  uint32_t ks2 = k0 ^ k1 ^ 0x1BD11BDAu;
  uint32_t x0 = c0 + k0, x1 = c1 + k1;
  for(int i=0;i<4;i++){ x0 += x1; x1 = rotl32(x1, ra[i]); x1 ^= x0; }
  x0 += k1; x1 += ks2 + 1u;
  for(int i=0;i<4;i++){ x0 += x1; x1 = rotl32(x1, rb[i]); x1 ^= x0; }
  x0 += ks2; x1 += k0 + 2u;
  for(int i=0;i<4;i++){ x0 += x1; x1 = rotl32(x1, ra[i]); x1 ^= x0; }
  x0 += k0; x1 += k1 + 3u;
  for(int i=0;i<4;i++){ x0 += x1; x1 = rotl32(x1, rb[i]); x1 ^= x0; }
  x0 += k1; x1 += ks2 + 4u;
  for(int i=0;i<4;i++){ x0 += x1; x1 = rotl32(x1, ra[i]); x1 ^= x0; }
  x0 += ks2; x1 += k0 + 5u;
  o0 = x0; o1 = x1;
}

static void jax_split_child(uint32_t ka, uint32_t kb, uint32_t i,
                            uint32_t& oa, uint32_t& ob){
  tf2x32(ka, kb, 0u, i, oa, ob);
}

static uint32_t jax_bits32(uint32_t ka, uint32_t kb, uint32_t i){
  uint32_t a,b; tf2x32(ka, kb, 0u, i, a, b);
  return a ^ b;
}

static void jax_perm64(uint32_t ka, uint32_t kb, int* perm){
  uint32_t sa, sb; jax_split_child(ka, kb, 1u, sa, sb);
  uint32_t b[64]; int v[64];
  for(int i=0;i<64;i++){ b[i]=jax_bits32(sa, sb, (uint32_t)i); v[i]=i; }
  for(int i=1;i<64;i++){
    uint32_t bb=b[i]; int vv=v[i]; int j=i-1;
    while(j>=0 && b[j]>bb){ b[j+1]=b[j]; v[j+1]=v[j]; j--; }
    b[j+1]=bb; v[j+1]=vv;
  }
  for(int i=0;i<64;i++) perm[i]=v[i];
}

static void compute_cols(ColsBoth& cb){
  uint32_t k1a,k1b,k2a,k2b;
  jax_split_child(0u, 42u, 0u, k1a, k1b);
  jax_split_child(0u, 42u, 1u, k2a, k2b);
  for(int side=0; side<2; side++){
    uint32_t ka = side ? k2a : k1a;
    uint32_t kb = side ? k2b : k1b;
    uint32_t nka,nkb, c1a,c1b, c2a,c2b;
    jax_split_child(ka,kb,0u,nka,nkb);
    jax_split_child(ka,kb,1u,c1a,c1b);
    jax_split_child(ka,kb,2u,c2a,c2b);
    int p[64];
    jax_perm64(c1a,c1b,p); for(int i=0;i<25;i++) cb.c[side].o25[i]=p[i];
    jax_perm64(c2a,c2b,p); for(int i=0;i<25;i++) cb.c[side].i25[i]=p[i];
    uint32_t d1a,d1b,d2a,d2b;
    jax_split_child(nka,nkb,1u,d1a,d1b);
    jax_split_child(nka,nkb,2u,d2a,d2b);
    jax_perm64(d1a,d1b,p); for(int i=0;i<10;i++) cb.c[side].o10[i]=p[i];
    jax_perm64(d2a,d2b,p); for(int i=0;i<10;i++) cb.c[side].i10[i]=p[i];
  }
}

// ---------------- device helpers ----------------
__device__ __forceinline__ float getc(const float4& v, int i){
  return (i==0)?v.x:(i==1)?v.y:(i==2)?v.z:v.w;
}
__device__ __forceinline__ float sigf(float x){ return 1.0f/(1.0f+expf(-x)); }
__device__ __forceinline__ void add4(float4& s, const float4& v){
  s.x+=v.x; s.y+=v.y; s.z+=v.z; s.w+=v.w;
}

// ---------------- kernels ----------------

// s_hop1[2][256][50]: per root node, 25 sampled out-neighbors then 25 in.
__global__ __launch_bounds__(256) void sample1_kernel(
    const int* __restrict__ nodes1, const int* __restrict__ nodes2,
    const int* __restrict__ nout, const int* __restrict__ nin,
    int* __restrict__ s_hop1, ColsBoth cb){
  int idx = blockIdx.x*blockDim.x + threadIdx.x;    // 25600
  if(idx >= 2*256*50) return;
  int side = idx / (256*50);
  int rem  = idx % (256*50);
  int b = rem / 50, j = rem % 50;
  int node = (side ? nodes2 : nodes1)[b];
  const Cols& c = cb.c[side];
  int nbr = (j < 25) ? nout[(long)node*64 + c.o25[j]]
                     : nin [(long)node*64 + c.i25[j-25]];
  s_hop1[idx] = nbr;
}

// Gather + mean-aggregate: one row per 32 lanes (lane covers 4 channels).
// Rows [0,512): hop0 (n=25). Rows [512,26112): hop1 (n=10, sample2 inline).
// All 20 hop-1 neighbor loads kept outstanding simultaneously (MLP).
__global__ __launch_bounds__(256) void gather_kernel(
    const float* __restrict__ feat,
    const int* __restrict__ nodes1, const int* __restrict__ nodes2,
    const int* __restrict__ s_hop1,
    const int* __restrict__ nout, const int* __restrict__ nin,
    float* __restrict__ agg, int base_row, ColsBoth cb)
{
  int t = threadIdx.x;
  int row_local = blockIdx.x*8 + (t>>5);
  int lane = t & 31;
  int c0 = lane*4;
  int row = base_row + row_local;

  float4 selfv, so, si;

  if(row < 512){                       // hop0: whole 8-row block uniform
    int side = row >> 8, b = row & 255;
    int node = (side ? nodes2 : nodes1)[b];
    selfv = *(const float4*)(feat + (long)node*FDIM + c0);
    const int* nb = s_hop1 + row*50;
    float4 acc = make_float4(0,0,0,0);
    #pragma unroll
    for(int jj=0; jj<25; jj+=5){       // batches of 5 (last batch of trailing 5 merged below)
      int id[5]; float4 v[5];
      #pragma unroll
      for(int i=0;i<5;i++) id[i] = nb[jj+i];
      #pragma unroll
      for(int i=0;i<5;i++) v[i] = *(const float4*)(feat + (long)id[i]*FDIM + c0);
      #pragma unroll
      for(int i=0;i<5;i++) add4(acc, v[i]);
    }
    so = make_float4(acc.x/25.f, acc.y/25.f, acc.z/25.f, acc.w/25.f);
    acc = make_float4(0,0,0,0);
    #pragma unroll
    for(int jj=25; jj<50; jj+=5){
      int id[5]; float4 v[5];
      #pragma unroll
      for(int i=0;i<5;i++) id[i] = nb[jj+i];
      #pragma unroll
      for(int i=0;i<5;i++) v[i] = *(const float4*)(feat + (long)id[i]*FDIM + c0);
      #pragma unroll
      for(int i=0;i<5;i++) add4(acc, v[i]);
    }
    si = make_float4(acc.x/25.f, acc.y/25.f, acc.z/25.f, acc.w/25.f);
  } else {                             // hop1: 20 loads all outstanding
    int hrow = row - 512;
    int side = (hrow >= 12800) ? 1 : 0;
    int node = s_hop1[hrow];
    const Cols& c = cb.c[side];
    const long nb = (long)node*64;
    int oid[10], iid[10];
    #pragma unroll
    for(int j=0;j<10;j++) oid[j] = nout[nb + c.o10[j]];
    #pragma unroll
    for(int j=0;j<10;j++) iid[j] = nin[nb + c.i10[j]];
    selfv = *(const float4*)(feat + (long)node*FDIM + c0);
    float4 v[20];
    #pragma unroll
    for(int j=0;j<10;j++) v[j]    = *(const float4*)(feat + (long)oid[j]*FDIM + c0);
    #pragma unroll
    for(int j=0;j<10;j++) v[10+j] = *(const float4*)(feat + (long)iid[j]*FDIM + c0);
    float4 acc = make_float4(0,0,0,0);
    #pragma unroll
    for(int j=0;j<10;j++) add4(acc, v[j]);
    so = make_float4(acc.x*0.1f, acc.y*0.1f, acc.z*0.1f, acc.w*0.1f);
    acc = make_float4(0,0,0,0);
    #pragma unroll
    for(int j=0;j<10;j++) add4(acc, v[10+j]);
    si = make_float4(acc.x*0.1f, acc.y*0.1f, acc.z*0.1f, acc.w*0.1f);
  }

  float* ar = agg + (long)row_local*KDIM;
  *(float4*)(ar + c0)       = selfv;
  *(float4*)(ar + 128 + c0) = so;
  *(float4*)(ar + 256 + c0) = si;
}

// Blocked GEMM + sigmoid: out[r][128] = sig(A[r][384] @ W[384][128]).
// 128 rows/block, thread = 8 rows x 8 cols -> 256 FMA per 8 ds_read_b128 (FMA-bound).
// W staged in LDS in 4 chunks of 96 k.
__global__ __launch_bounds__(256) void gemm_sig_kernel(
    const float* __restrict__ A, const float* __restrict__ W,
    float* __restrict__ out)
{
  __shared__ float Wbuf[96*128];       // 48 KB
  int t = threadIdx.x, lane = t&15, rg = t>>4;
  int r0 = blockIdx.x*128 + rg*8;
  int c0 = lane*8;
  float acc[8][8];
  #pragma unroll
  for(int r=0;r<8;r++)
    #pragma unroll
    for(int i=0;i<8;i++) acc[r][i]=0.f;

  for(int kc=0; kc<4; kc++){
    __syncthreads();
    const float4* ws = (const float4*)(W + kc*96*128);
    float4* wd = (float4*)Wbuf;
    #pragma unroll
    for(int i=0;i<12;i++) wd[i*256+t] = ws[i*256+t];
    __syncthreads();
    const float* Ab = A + (long)r0*KDIM + kc*96;
    for(int k4=0;k4<96;k4+=4){
      float4 a[8];
      #pragma unroll
      for(int r=0;r<8;r++) a[r] = *(const float4*)(Ab + r*KDIM + k4);
      #pragma unroll
      for(int kk=0;kk<4;kk++){
        const float* wr = Wbuf + (k4+kk)*128 + c0;
        float4 w0 = *(const float4*)wr;
        float4 w1 = *(const float4*)(wr+4);
        #pragma unroll
        for(int r=0;r<8;r++){
          float av = getc(a[r],kk);
          acc[r][0]+=av*w0.x; acc[r][1]+=av*w0.y; acc[r][2]+=av*w0.z; acc[r][3]+=av*w0.w;
          acc[r][4]+=av*w1.x; acc[r][5]+=av*w1.y; acc[r][6]+=av*w1.z; acc[r][7]+=av*w1.w;
        }
      }
    }
  }
  #pragma unroll
  for(int r=0;r<8;r++){
    float4 o0, o1;
    o0.x=sigf(acc[r][0]); o0.y=sigf(acc[r][1]); o0.z=sigf(acc[r][2]); o0.w=sigf(acc[r][3]);
    o1.x=sigf(acc[r][4]); o1.y=sigf(acc[r][5]); o1.z=sigf(acc[r][6]); o1.w=sigf(acc[r][7]);
    float* op = out + (long)(r0+r)*FDIM + c0;
    *(float4*)op = o0; *(float4*)(op+4) = o1;
  }
}

// Fused layer-1 agg + head GEMM + sigmoid + 128->64 projection.
// grid 96 = head(3) x 32 tiles of 16 rows. h is 13.4 MB -> L2-resident, so the
// 3x redundant agg reads are cheap; W/D read straight from L2 (196 KB x 96 = 19 MB L2).
__global__ __launch_bounds__(256) void agghead_kernel(
    const float* __restrict__ h,        // [26112][128]: rows 0..511 = h0, 512.. = h1
    const float* __restrict__ Wm, const float* __restrict__ Ws, const float* __restrict__ Wp,
    const float* __restrict__ Dm, const float* __restrict__ Ds, const float* __restrict__ Dp,
    float* __restrict__ out)            // [6][256][64]
{
  __shared__ float agg[16][388];
  __shared__ float hb[16][132];
  int head = blockIdx.x >> 5, tile = blockIdx.x & 31;
  int t = threadIdx.x, lane = t&15, rg = t>>4;
  int row = tile*16 + rg;               // 0..511
  int c0 = lane*8;
  const float* W = (head==0) ? Wm : (head==1) ? Ws : Wp;
  const float* D = (head==0) ? Dm : (head==1) ? Ds : Dp;

  // phase 1: aggregate. self from h[row], neighbors h[512 + row*50 + j].
  {
    const float* sp = h + (long)row*FDIM + c0;
    *(float4*)&agg[rg][c0]   = *(const float4*)sp;
    *(float4*)&agg[rg][c0+4] = *(const float4*)(sp+4);
    const float* base = h + (long)(512 + row*50)*FDIM + c0;
    float4 s0 = make_float4(0,0,0,0), s1 = make_float4(0,0,0,0);
    #pragma unroll
    for(int jj=0;jj<25;jj+=5){
      float4 v0[5], v1[5];
      #pragma unroll
      for(int i=0;i<5;i++){
        const float* fp = base + (long)(jj+i)*FDIM;
        v0[i] = *(const float4*)fp; v1[i] = *(const float4*)(fp+4);
      }
      #pragma unroll
      for(int i=0;i<5;i++){ add4(s0, v0[i]); add4(s1, v1[i]); }
    }
    const float inv = 1.0f/25.0f;
    *(float4*)&agg[rg][128+c0]   = make_float4(s0.x*inv,s0.y*inv,s0.z*inv,s0.w*inv);
    *(float4*)&agg[rg][128+c0+4] = make_float4(s1.x*inv,s1.y*inv,s1.z*inv,s1.w*inv);
    s0 = make_float4(0,0,0,0); s1 = make_float4(0,0,0,0);
    #pragma unroll
    for(int jj=25;jj<50;jj+=5){
      float4 v0[5], v1[5];
      #pragma unroll
      for(int i=0;i<5;i++){
        const float* fp = base + (long)(jj+i)*FDIM;
        v0[i] = *(const float4*)fp; v1[i] = *(const float4*)(fp+4);
      }
      #pragma unroll
      for(int i=0;i<5;i++){ add4(s0, v0[i]); add4(s1, v1[i]); }
    }
    *(float4*)&agg[rg][256+c0]   = make_float4(s0.x*inv,s0.y*inv,s0.z*inv,s0.w*inv);
    *(float4*)&agg[rg][256+c0+4] = make_float4(s1.x*inv,s1.y*inv,s1.z*inv,s1.w*inv);
  }
  __syncthreads();

  // phase 2: GEMM 384->128 + sigmoid (W from L2, unrolled for outstanding loads)
  {
    float acc[8] = {0,0,0,0,0,0,0,0};
    #pragma unroll 4
    for(int k=0;k<KDIM;k++){
      float a = agg[rg][k];
      const float* wr = W + (long)k*FDIM + c0;
      float4 w0 = *(const float4*)wr; float4 w1 = *(const float4*)(wr+4);
      acc[0]+=a*w0.x; acc[1]+=a*w0.y; acc[2]+=a*w0.z; acc[3]+=a*w0.w;
      acc[4]+=a*w1.x; acc[5]+=a*w1.y; acc[6]+=a*w1.z; acc[7]+=a*w1.w;
    }
    #pragma unroll
    for(int i=0;i<8;i++) hb[rg][c0+i] = sigf(acc[i]);
  }
  __syncthreads();

  // phase 3: projection 128->64 (D 32 KB, L2-resident broadcast)
  {
    int cd = lane*4;
    float a0=0,a1=0,a2=0,a3=0;
    #pragma unroll 4
    for(int k=0;k<FDIM;k++){
      float hv = hb[rg][k];
      const float* dr = D + (long)k*64 + cd;
      float4 d = *(const float4*)dr;
      a0 += hv*d.x; a1 += hv*d.y; a2 += hv*d.z; a3 += hv*d.w;
    }
    int side = row >> 8, b = row & 255;
    float* op = out + ((long)(side*3+head)*256 + b)*64 + cd;
    *(float4*)op = make_float4(a0,a1,a2,a3);
  }
}

// ---------------- launch ----------------
extern "C" void kernel_launch(void* const* d_in, const int* in_sizes, int n_in,
                              void* d_out, int out_size, void* d_ws, size_t ws_size,
                              hipStream_t stream) {
  const int*   nodes1  = (const int*)d_in[0];
  const int*   nodes2  = (const int*)d_in[1];
  const int*   nout    = (const int*)d_in[2];
  const int*   nin     = (const int*)d_in[3];
  const float* feat    = (const float*)d_in[4];
  const float* W_in    = (const float*)d_in[5];
  const float* W_mean  = (const float*)d_in[6];
  const float* W_std   = (const float*)d_in[7];
  const float* W_pi    = (const float*)d_in[8];
  const float* Wd_mean = (const float*)d_in[11];
  const float* Wd_std  = (const float*)d_in[12];
  const float* Wd_pi   = (const float*)d_in[13];
  float* out = (float*)d_out;

  // workspace: s_hop1 | h[26112][128] | aggChunk
  int*   s_hop1 = (int*)d_ws;                          // 25600 ints
  float* h      = (float*)(s_hop1 + 25600);            // 26112*128
  float* aggC   = h + (size_t)NROWS*FDIM;

  // chunk count: smallest that fits ws (constant per session -> graph-safe).
  // chunkRows must be divisible by 128 (gemm) and 8 (gather).
  size_t fixedB = 25600*4 + (size_t)NROWS*FDIM*4;
  const int ncOpt[5] = {1,2,4,12,51};
  int nc = 51;
  for(int i=0;i<5;i++){
    size_t need = fixedB + ((size_t)NROWS/ncOpt[i])*KDIM*4;
    if(need <= ws_size){ nc = ncOpt[i]; break; }
  }
  int chunkRows = NROWS / nc;

  ColsBoth cb;
  compute_cols(cb);

  sample1_kernel<<<(2*256*50 + 255)/256, 256, 0, stream>>>(nodes1, nodes2, nout, nin, s_hop1, cb);
  for(int c=0;c<nc;c++){
    int base = c*chunkRows;
    gather_kernel<<<chunkRows/8, 256, 0, stream>>>(feat, nodes1, nodes2, s_hop1,
                                                   nout, nin, aggC, base, cb);
    gemm_sig_kernel<<<chunkRows/128, 256, 0, stream>>>(aggC, W_in, h + (size_t)base*FDIM);
  }
  agghead_kernel<<<96, 256, 0, stream>>>(h, W_mean, W_std, W_pi, Wd_mean, Wd_std, Wd_pi, out);
}

// Round 6
// 331.055 us; speedup vs baseline: 1.0743x; 1.0743x over previous
//
#include <hip/hip_runtime.h>
#include <stdint.h>
#include <math.h>

#define FDIM 128
#define KDIM 384
#define NROWS 26112   // 512 hop0 rows + 25600 hop1 rows

struct Cols { int o25[25]; int i25[25]; int o10[10]; int i10[10]; };
struct ColsBoth { Cols c[2]; };

// ---------------- host-side JAX threefry (partitionable=True) ----------------
static inline uint32_t rotl32(uint32_t x, uint32_t r){ return (x<<r)|(x>>(32u-r)); }

static void tf2x32(uint32_t k0, uint32_t k1, uint32_t c0, uint32_t c1,
                   uint32_t& o0, uint32_t& o1){
  const uint32_t ra[4] = {13u,15u,26u,6u};
  const uint32_t rb[4] = {17u,29u,16u,24u};
  uint32_t ks2 = k0 ^ k1 ^ 0x1BD11BDAu;
  uint32_t x0 = c0 + k0, x1 = c1 + k1;
  for(int i=0;i<4;i++){ x0 += x1; x1 = rotl32(x1, ra[i]); x1 ^= x0; }
  x0 += k1; x1 += ks2 + 1u;
  for(int i=0;i<4;i++){ x0 += x1; x1 = rotl32(x1, rb[i]); x1 ^= x0; }
  x0 += ks2; x1 += k0 + 2u;
  for(int i=0;i<4;i++){ x0 += x1; x1 = rotl32(x1, ra[i]); x1 ^= x0; }
  x0 += k0; x1 += k1 + 3u;
  for(int i=0;i<4;i++){ x0 += x1; x1 = rotl32(x1, rb[i]); x1 ^= x0; }
  x0 += k1; x1 += ks2 + 4u;
  for(int i=0;i<4;i++){ x0 += x1; x1 = rotl32(x1, ra[i]); x1 ^= x0; }
  x0 += ks2; x1 += k0 + 5u;
  o0 = x0; o1 = x1;
}

static void jax_split_child(uint32_t ka, uint32_t kb, uint32_t i,
                            uint32_t& oa, uint32_t& ob){
  tf2x32(ka, kb, 0u, i, oa, ob);
}

static uint32_t jax_bits32(uint32_t ka, uint32_t kb, uint32_t i){
  uint32_t a,b; tf2x32(ka, kb, 0u, i, a, b);
  return a ^ b;
}

static void jax_perm64(uint32_t ka, uint32_t kb, int* perm){
  uint32_t sa, sb; jax_split_child(ka, kb, 1u, sa, sb);
  uint32_t b[64]; int v[64];
  for(int i=0;i<64;i++){ b[i]=jax_bits32(sa, sb, (uint32_t)i); v[i]=i; }
  for(int i=1;i<64;i++){
    uint32_t bb=b[i]; int vv=v[i]; int j=i-1;
    while(j>=0 && b[j]>bb){ b[j+1]=b[j]; v[j+1]=v[j]; j--; }
    b[j+1]=bb; v[j+1]=vv;
  }
  for(int i=0;i<64;i++) perm[i]=v[i];
}

static void compute_cols(ColsBoth& cb){
  uint32_t k1a,k1b,k2a,k2b;
  jax_split_child(0u, 42u, 0u, k1a, k1b);
  jax_split_child(0u, 42u, 1u, k2a, k2b);
  for(int side=0; side<2; side++){
    uint32_t ka = side ? k2a : k1a;
    uint32_t kb = side ? k2b : k1b;
    uint32_t nka,nkb, c1a,c1b, c2a,c2b;
    jax_split_child(ka,kb,0u,nka,nkb);
    jax_split_child(ka,kb,1u,c1a,c1b);
    jax_split_child(ka,kb,2u,c2a,c2b);
    int p[64];
    jax_perm64(c1a,c1b,p); for(int i=0;i<25;i++) cb.c[side].o25[i]=p[i];
    jax_perm64(c2a,c2b,p); for(int i=0;i<25;i++) cb.c[side].i25[i]=p[i];
    uint32_t d1a,d1b,d2a,d2b;
    jax_split_child(nka,nkb,1u,d1a,d1b);
    jax_split_child(nka,nkb,2u,d2a,d2b);
    jax_perm64(d1a,d1b,p); for(int i=0;i<10;i++) cb.c[side].o10[i]=p[i];
    jax_perm64(d2a,d2b,p); for(int i=0;i<10;i++) cb.c[side].i10[i]=p[i];
  }
}

// ---------------- device helpers ----------------
__device__ __forceinline__ float getc(const float4& v, int i){
  return (i==0)?v.x:(i==1)?v.y:(i==2)?v.z:v.w;
}
__device__ __forceinline__ float sigf(float x){ return 1.0f/(1.0f+expf(-x)); }
__device__ __forceinline__ void add4(float4& s, const float4& v){
  s.x+=v.x; s.y+=v.y; s.z+=v.z; s.w+=v.w;
}

// ---------------- kernels ----------------

// s_hop1[2][256][50]: per root node, 25 sampled out-neighbors then 25 in.
__global__ __launch_bounds__(256) void sample1_kernel(
    const int* __restrict__ nodes1, const int* __restrict__ nodes2,
    const int* __restrict__ nout, const int* __restrict__ nin,
    int* __restrict__ s_hop1, ColsBoth cb){
  int idx = blockIdx.x*blockDim.x + threadIdx.x;    // 25600
  if(idx >= 2*256*50) return;
  int side = idx / (256*50);
  int rem  = idx % (256*50);
  int b = rem / 50, j = rem % 50;
  int node = (side ? nodes2 : nodes1)[b];
  const Cols& c = cb.c[side];
  int nbr = (j < 25) ? nout[(long)node*64 + c.o25[j]]
                     : nin [(long)node*64 + c.i25[j-25]];
  s_hop1[idx] = nbr;
}

// Gather + mean-aggregate: one row per 32 lanes (lane covers 4 channels).
__global__ __launch_bounds__(256) void gather_kernel(
    const float* __restrict__ feat,
    const int* __restrict__ nodes1, const int* __restrict__ nodes2,
    const int* __restrict__ s_hop1,
    const int* __restrict__ nout, const int* __restrict__ nin,
    float* __restrict__ agg, int base_row, ColsBoth cb)
{
  int t = threadIdx.x;
  int row_local = blockIdx.x*8 + (t>>5);
  int lane = t & 31;
  int c0 = lane*4;
  int row = base_row + row_local;

  float4 selfv, so, si;

  if(row < 512){                       // hop0
    int side = row >> 8, b = row & 255;
    int node = (side ? nodes2 : nodes1)[b];
    selfv = *(const float4*)(feat + (long)node*FDIM + c0);
    const int* nb = s_hop1 + row*50;
    float4 acc = make_float4(0,0,0,0);
    #pragma unroll
    for(int jj=0; jj<25; jj+=5){
      int id[5]; float4 v[5];
      #pragma unroll
      for(int i=0;i<5;i++) id[i] = nb[jj+i];
      #pragma unroll
      for(int i=0;i<5;i++) v[i] = *(const float4*)(feat + (long)id[i]*FDIM + c0);
      #pragma unroll
      for(int i=0;i<5;i++) add4(acc, v[i]);
    }
    so = make_float4(acc.x/25.f, acc.y/25.f, acc.z/25.f, acc.w/25.f);
    acc = make_float4(0,0,0,0);
    #pragma unroll
    for(int jj=25; jj<50; jj+=5){
      int id[5]; float4 v[5];
      #pragma unroll
      for(int i=0;i<5;i++) id[i] = nb[jj+i];
      #pragma unroll
      for(int i=0;i<5;i++) v[i] = *(const float4*)(feat + (long)id[i]*FDIM + c0);
      #pragma unroll
      for(int i=0;i<5;i++) add4(acc, v[i]);
    }
    si = make_float4(acc.x/25.f, acc.y/25.f, acc.z/25.f, acc.w/25.f);
  } else {                             // hop1: 20 loads outstanding
    int hrow = row - 512;
    int side = (hrow >= 12800) ? 1 : 0;
    int node = s_hop1[hrow];
    const Cols& c = cb.c[side];
    const long nb = (long)node*64;
    int oid[10], iid[10];
    #pragma unroll
    for(int j=0;j<10;j++) oid[j] = nout[nb + c.o10[j]];
    #pragma unroll
    for(int j=0;j<10;j++) iid[j] = nin[nb + c.i10[j]];
    selfv = *(const float4*)(feat + (long)node*FDIM + c0);
    float4 v[20];
    #pragma unroll
    for(int j=0;j<10;j++) v[j]    = *(const float4*)(feat + (long)oid[j]*FDIM + c0);
    #pragma unroll
    for(int j=0;j<10;j++) v[10+j] = *(const float4*)(feat + (long)iid[j]*FDIM + c0);
    float4 acc = make_float4(0,0,0,0);
    #pragma unroll
    for(int j=0;j<10;j++) add4(acc, v[j]);
    so = make_float4(acc.x*0.1f, acc.y*0.1f, acc.z*0.1f, acc.w*0.1f);
    acc = make_float4(0,0,0,0);
    #pragma unroll
    for(int j=0;j<10;j++) add4(acc, v[10+j]);
    si = make_float4(acc.x*0.1f, acc.y*0.1f, acc.z*0.1f, acc.w*0.1f);
  }

  float* ar = agg + (long)row_local*KDIM;
  *(float4*)(ar + c0)       = selfv;
  *(float4*)(ar + 128 + c0) = so;
  *(float4*)(ar + 256 + c0) = si;
}

// Blocked GEMM + sigmoid: 64 rows/block (408 blocks), thread = 4 rows x 8 cols.
// W staged in LDS in 4 chunks of 96 k. (Reverted from 128-row/8x8 to de-confound R5.)
__global__ __launch_bounds__(256) void gemm_sig_kernel(
    const float* __restrict__ A, const float* __restrict__ W,
    float* __restrict__ out)
{
  __shared__ float Wbuf[96*128];       // 48 KB
  int t = threadIdx.x, lane = t&15, rg = t>>4;
  int r0 = blockIdx.x*64 + rg*4;
  int c0 = lane*8;
  float acc[4][8];
  #pragma unroll
  for(int r=0;r<4;r++)
    #pragma unroll
    for(int i=0;i<8;i++) acc[r][i]=0.f;

  for(int kc=0; kc<4; kc++){
    __syncthreads();
    const float4* ws = (const float4*)(W + kc*96*128);
    float4* wd = (float4*)Wbuf;
    #pragma unroll
    for(int i=0;i<12;i++) wd[i*256+t] = ws[i*256+t];
    __syncthreads();
    const float* Ab = A + (long)r0*KDIM + kc*96;
    #pragma unroll 2
    for(int k4=0;k4<96;k4+=4){
      float4 a0 = *(const float4*)(Ab + 0*KDIM + k4);
      float4 a1 = *(const float4*)(Ab + 1*KDIM + k4);
      float4 a2 = *(const float4*)(Ab + 2*KDIM + k4);
      float4 a3 = *(const float4*)(Ab + 3*KDIM + k4);
      #pragma unroll
      for(int kk=0;kk<4;kk++){
        float av0=getc(a0,kk), av1=getc(a1,kk), av2=getc(a2,kk), av3=getc(a3,kk);
        const float* wr = Wbuf + (k4+kk)*128 + c0;
        float4 w0 = *(const float4*)wr;
        float4 w1 = *(const float4*)(wr+4);
        acc[0][0]+=av0*w0.x; acc[0][1]+=av0*w0.y; acc[0][2]+=av0*w0.z; acc[0][3]+=av0*w0.w;
        acc[0][4]+=av0*w1.x; acc[0][5]+=av0*w1.y; acc[0][6]+=av0*w1.z; acc[0][7]+=av0*w1.w;
        acc[1][0]+=av1*w0.x; acc[1][1]+=av1*w0.y; acc[1][2]+=av1*w0.z; acc[1][3]+=av1*w0.w;
        acc[1][4]+=av1*w1.x; acc[1][5]+=av1*w1.y; acc[1][6]+=av1*w1.z; acc[1][7]+=av1*w1.w;
        acc[2][0]+=av2*w0.x; acc[2][1]+=av2*w0.y; acc[2][2]+=av2*w0.z; acc[2][3]+=av2*w0.w;
        acc[2][4]+=av2*w1.x; acc[2][5]+=av2*w1.y; acc[2][6]+=av2*w1.z; acc[2][7]+=av2*w1.w;
        acc[3][0]+=av3*w0.x; acc[3][1]+=av3*w0.y; acc[3][2]+=av3*w0.z; acc[3][3]+=av3*w0.w;
        acc[3][4]+=av3*w1.x; acc[3][5]+=av3*w1.y; acc[3][6]+=av3*w1.z; acc[3][7]+=av3*w1.w;
      }
    }
  }
  #pragma unroll
  for(int r=0;r<4;r++){
    float4 o0, o1;
    o0.x=sigf(acc[r][0]); o0.y=sigf(acc[r][1]); o0.z=sigf(acc[r][2]); o0.w=sigf(acc[r][3]);
    o1.x=sigf(acc[r][4]); o1.y=sigf(acc[r][5]); o1.z=sigf(acc[r][6]); o1.w=sigf(acc[r][7]);
    float* op = out + (long)(r0+r)*FDIM + c0;
    *(float4*)op = o0; *(float4*)(op+4) = o1;
  }
}

// Layer-1 aggregation: agg2[row][384] = [h0_self | mean(h1 out 25) | mean(h1 in 25)]
// 512 blocks, parallel over channels/halves (proven cheap shape).
__global__ __launch_bounds__(256) void agg1_kernel(
    const float* __restrict__ h0, const float* __restrict__ h1,
    float* __restrict__ agg2)
{
  int row = blockIdx.x;               // 0..511
  int t = threadIdx.x;
  int ch = t & 127;
  int half = t >> 7;
  const float* base = h1 + (long)row*50*FDIM + half*25*FDIM + ch;
  float s = 0.f;
  #pragma unroll
  for(int j=0;j<25;j++) s += base[j*FDIM];
  agg2[(long)row*KDIM + 128 + half*128 + ch] = s * (1.0f/25.0f);
  if(half == 0) agg2[(long)row*KDIM + ch] = h0[(long)row*FDIM + ch];
}

// Head GEMM: grid 384 = 3 heads x 128 row-quads. Block: 4 rows x 128 cols, K=384.
// A row-quad staged in LDS; thread = (row = t>>6, cols = (t&63)*2 .. +1).
// Wave reads W[k][0..127] contiguous (L2-resident). Fused sigmoid + 128->64 proj.
__global__ __launch_bounds__(256) void head_kernel(
    const float* __restrict__ agg2,
    const float* __restrict__ Wm, const float* __restrict__ Ws, const float* __restrict__ Wp,
    const float* __restrict__ Dm, const float* __restrict__ Ds, const float* __restrict__ Dp,
    float* __restrict__ out)            // [6][256][64]
{
  __shared__ float As[4*KDIM];          // 6 KB
  __shared__ float Hs[4*FDIM];          // 2 KB
  int head = blockIdx.x >> 7;           // 0..2
  int rt   = blockIdx.x & 127;          // 0..127
  int t = threadIdx.x;
  int row = t >> 6;                     // 0..3 (local)
  int c = (t & 63) * 2;                 // 0..126
  const float* W = (head==0) ? Wm : (head==1) ? Ws : Wp;
  const float* D = (head==0) ? Dm : (head==1) ? Ds : Dp;

  // stage A quad: 4*384 = 1536 floats, 256 threads x 6
  {
    const float* src = agg2 + (long)rt*4*KDIM;
    #pragma unroll
    for(int i=0;i<6;i++) As[i*256 + t] = src[i*256 + t];
  }
  __syncthreads();

  // GEMM: 2 cols per thread, K=384
  float acc0 = 0.f, acc1 = 0.f;
  const float* as = As + row*KDIM;
  #pragma unroll 8
  for(int k=0;k<KDIM;k++){
    float a = as[k];
    float2 w = *(const float2*)(W + (long)k*FDIM + c);
    acc0 += a*w.x; acc1 += a*w.y;
  }
  Hs[row*FDIM + c]   = sigf(acc0);
  Hs[row*FDIM + c+1] = sigf(acc1);
  __syncthreads();

  // projection: 256 outputs (4 rows x 64 cols), one per thread
  {
    int col = t & 63;
    const float* hs = Hs + row*FDIM;
    float a = 0.f;
    #pragma unroll 8
    for(int k=0;k<FDIM;k++){
      a += hs[k] * D[(long)k*64 + col];
    }
    int grow = rt*4 + row;              // 0..511
    int side = grow >> 8, b = grow & 255;
    out[((long)(side*3+head)*256 + b)*64 + col] = a;
  }
}

// ---------------- launch ----------------
extern "C" void kernel_launch(void* const* d_in, const int* in_sizes, int n_in,
                              void* d_out, int out_size, void* d_ws, size_t ws_size,
                              hipStream_t stream) {
  const int*   nodes1  = (const int*)d_in[0];
  const int*   nodes2  = (const int*)d_in[1];
  const int*   nout    = (const int*)d_in[2];
  const int*   nin     = (const int*)d_in[3];
  const float* feat    = (const float*)d_in[4];
  const float* W_in    = (const float*)d_in[5];
  const float* W_mean  = (const float*)d_in[6];
  const float* W_std   = (const float*)d_in[7];
  const float* W_pi    = (const float*)d_in[8];
  const float* Wd_mean = (const float*)d_in[11];
  const float* Wd_std  = (const float*)d_in[12];
  const float* Wd_pi   = (const float*)d_in[13];
  float* out = (float*)d_out;

  // workspace: s_hop1 | h[26112][128] | agg2[512][384] | aggChunk
  int*   s_hop1 = (int*)d_ws;                          // 25600 ints
  float* h      = (float*)(s_hop1 + 25600);            // 26112*128
  float* agg2   = h + (size_t)NROWS*FDIM;              // 512*384
  float* aggC   = agg2 + 512*KDIM;

  // chunk count: smallest that fits ws (constant per session -> graph-safe).
  // chunkRows divisible by 64 (gemm) and 8 (gather).
  size_t fixedB = 25600*4 + (size_t)NROWS*FDIM*4 + 512*KDIM*4;
  const int ncOpt[5] = {1,2,4,12,51};
  int nc = 51;
  for(int i=0;i<5;i++){
    size_t need = fixedB + ((size_t)NROWS/ncOpt[i])*KDIM*4;
    if(need <= ws_size){ nc = ncOpt[i]; break; }
  }
  int chunkRows = NROWS / nc;

  ColsBoth cb;
  compute_cols(cb);

  sample1_kernel<<<(2*256*50 + 255)/256, 256, 0, stream>>>(nodes1, nodes2, nout, nin, s_hop1, cb);
  for(int c=0;c<nc;c++){
    int base = c*chunkRows;
    gather_kernel<<<chunkRows/8, 256, 0, stream>>>(feat, nodes1, nodes2, s_hop1,
                                                   nout, nin, aggC, base, cb);
    gemm_sig_kernel<<<chunkRows/64, 256, 0, stream>>>(aggC, W_in, h + (size_t)base*FDIM);
  }
  agg1_kernel<<<512, 256, 0, stream>>>(h, h + 512*FDIM, agg2);
  head_kernel<<<384, 256, 0, stream>>>(agg2, W_mean, W_std, W_pi, Wd_mean, Wd_std, Wd_pi, out);
}

// Round 7
// 323.764 us; speedup vs baseline: 1.0985x; 1.0225x over previous
//
#include <hip/hip_runtime.h>
#include <stdint.h>
#include <math.h>

#define FDIM 128
#define KDIM 384
#define NROWS 26112   // 512 hop0 rows + 25600 hop1 rows

struct Cols { int o25[25]; int i25[25]; int o10[10]; int i10[10]; };
struct ColsBoth { Cols c[2]; };

// ---------------- host-side JAX threefry (partitionable=True) ----------------
static inline uint32_t rotl32(uint32_t x, uint32_t r){ return (x<<r)|(x>>(32u-r)); }

static void tf2x32(uint32_t k0, uint32_t k1, uint32_t c0, uint32_t c1,
                   uint32_t& o0, uint32_t& o1){
  const uint32_t ra[4] = {13u,15u,26u,6u};
  const uint32_t rb[4] = {17u,29u,16u,24u};
  uint32_t ks2 = k0 ^ k1 ^ 0x1BD11BDAu;
  uint32_t x0 = c0 + k0, x1 = c1 + k1;
  for(int i=0;i<4;i++){ x0 += x1; x1 = rotl32(x1, ra[i]); x1 ^= x0; }
  x0 += k1; x1 += ks2 + 1u;
  for(int i=0;i<4;i++){ x0 += x1; x1 = rotl32(x1, rb[i]); x1 ^= x0; }
  x0 += ks2; x1 += k0 + 2u;
  for(int i=0;i<4;i++){ x0 += x1; x1 = rotl32(x1, ra[i]); x1 ^= x0; }
  x0 += k0; x1 += k1 + 3u;
  for(int i=0;i<4;i++){ x0 += x1; x1 = rotl32(x1, rb[i]); x1 ^= x0; }
  x0 += k1; x1 += ks2 + 4u;
  for(int i=0;i<4;i++){ x0 += x1; x1 = rotl32(x1, ra[i]); x1 ^= x0; }
  x0 += ks2; x1 += k0 + 5u;
  o0 = x0; o1 = x1;
}

static void jax_split_child(uint32_t ka, uint32_t kb, uint32_t i,
                            uint32_t& oa, uint32_t& ob){
  tf2x32(ka, kb, 0u, i, oa, ob);
}

static uint32_t jax_bits32(uint32_t ka, uint32_t kb, uint32_t i){
  uint32_t a,b; tf2x32(ka, kb, 0u, i, a, b);
  return a ^ b;
}

static void jax_perm64(uint32_t ka, uint32_t kb, int* perm){
  uint32_t sa, sb; jax_split_child(ka, kb, 1u, sa, sb);
  uint32_t b[64]; int v[64];
  for(int i=0;i<64;i++){ b[i]=jax_bits32(sa, sb, (uint32_t)i); v[i]=i; }
  for(int i=1;i<64;i++){
    uint32_t bb=b[i]; int vv=v[i]; int j=i-1;
    while(j>=0 && b[j]>bb){ b[j+1]=b[j]; v[j+1]=v[j]; j--; }
    b[j+1]=bb; v[j+1]=vv;
  }
  for(int i=0;i<64;i++) perm[i]=v[i];
}

static void compute_cols(ColsBoth& cb){
  uint32_t k1a,k1b,k2a,k2b;
  jax_split_child(0u, 42u, 0u, k1a, k1b);
  jax_split_child(0u, 42u, 1u, k2a, k2b);
  for(int side=0; side<2; side++){
    uint32_t ka = side ? k2a : k1a;
    uint32_t kb = side ? k2b : k1b;
    uint32_t nka,nkb, c1a,c1b, c2a,c2b;
    jax_split_child(ka,kb,0u,nka,nkb);
    jax_split_child(ka,kb,1u,c1a,c1b);
    jax_split_child(ka,kb,2u,c2a,c2b);
    int p[64];
    jax_perm64(c1a,c1b,p); for(int i=0;i<25;i++) cb.c[side].o25[i]=p[i];
    jax_perm64(c2a,c2b,p); for(int i=0;i<25;i++) cb.c[side].i25[i]=p[i];
    uint32_t d1a,d1b,d2a,d2b;
    jax_split_child(nka,nkb,1u,d1a,d1b);
    jax_split_child(nka,nkb,2u,d2a,d2b);
    jax_perm64(d1a,d1b,p); for(int i=0;i<10;i++) cb.c[side].o10[i]=p[i];
    jax_perm64(d2a,d2b,p); for(int i=0;i<10;i++) cb.c[side].i10[i]=p[i];
  }
}

// ---------------- device helpers ----------------
__device__ __forceinline__ float getc(const float4& v, int i){
  return (i==0)?v.x:(i==1)?v.y:(i==2)?v.z:v.w;
}
__device__ __forceinline__ float sigf(float x){ return 1.0f/(1.0f+expf(-x)); }
__device__ __forceinline__ void add4(float4& s, const float4& v){
  s.x+=v.x; s.y+=v.y; s.z+=v.z; s.w+=v.w;
}
__device__ __forceinline__ void add2(float2& s, const float2& v){
  s.x+=v.x; s.y+=v.y;
}

// ---------------- kernels ----------------

// Gather + mean-aggregate with sampling fused inline.
// One row per 32 lanes (lane covers 4 channels). 8 rows/block, 3264 blocks.
// Rows [0,512): hop0 (root self + 25 out + 25 in, ids from nout/nin[root]).
// Rows [512,26112): hop1 (node derived root->parent-col->node, then 10 out + 10 in).
__global__ __launch_bounds__(256) void gather_kernel(
    const float* __restrict__ feat,
    const int* __restrict__ nodes1, const int* __restrict__ nodes2,
    const int* __restrict__ nout, const int* __restrict__ nin,
    float* __restrict__ agg, int base_row, ColsBoth cb)
{
  int t = threadIdx.x;
  int row_local = blockIdx.x*8 + (t>>5);
  int lane = t & 31;
  int c0 = lane*4;
  int row = base_row + row_local;

  float4 selfv, so, si;

  if(row < 512){                       // hop0
    int side = row >> 8, b = row & 255;
    int node = (side ? nodes2 : nodes1)[b];
    const Cols& c = cb.c[side];
    const long nb = (long)node*64;
    selfv = *(const float4*)(feat + (long)node*FDIM + c0);
    float4 acc = make_float4(0,0,0,0);
    #pragma unroll
    for(int jj=0; jj<25; jj+=5){
      int id[5]; float4 v[5];
      #pragma unroll
      for(int i=0;i<5;i++) id[i] = nout[nb + c.o25[jj+i]];
      #pragma unroll
      for(int i=0;i<5;i++) v[i] = *(const float4*)(feat + (long)id[i]*FDIM + c0);
      #pragma unroll
      for(int i=0;i<5;i++) add4(acc, v[i]);
    }
    so = make_float4(acc.x/25.f, acc.y/25.f, acc.z/25.f, acc.w/25.f);
    acc = make_float4(0,0,0,0);
    #pragma unroll
    for(int jj=0; jj<25; jj+=5){
      int id[5]; float4 v[5];
      #pragma unroll
      for(int i=0;i<5;i++) id[i] = nin[nb + c.i25[jj+i]];
      #pragma unroll
      for(int i=0;i<5;i++) v[i] = *(const float4*)(feat + (long)id[i]*FDIM + c0);
      #pragma unroll
      for(int i=0;i<5;i++) add4(acc, v[i]);
    }
    si = make_float4(acc.x/25.f, acc.y/25.f, acc.z/25.f, acc.w/25.f);
  } else {                             // hop1
    int hrow = row - 512;
    int side = (hrow >= 12800) ? 1 : 0;
    int r = side ? (hrow - 12800) : hrow;
    int b = r / 50, slot = r % 50;
    const Cols& c = cb.c[side];
    int root = (side ? nodes2 : nodes1)[b];
    int node;
    if(slot < 25) node = nout[(long)root*64 + c.o25[slot]];
    else          node = nin [(long)root*64 + c.i25[slot-25]];
    const long nb = (long)node*64;
    int oid[10], iid[10];
    #pragma unroll
    for(int j=0;j<10;j++) oid[j] = nout[nb + c.o10[j]];
    #pragma unroll
    for(int j=0;j<10;j++) iid[j] = nin[nb + c.i10[j]];
    selfv = *(const float4*)(feat + (long)node*FDIM + c0);
    float4 v[20];
    #pragma unroll
    for(int j=0;j<10;j++) v[j]    = *(const float4*)(feat + (long)oid[j]*FDIM + c0);
    #pragma unroll
    for(int j=0;j<10;j++) v[10+j] = *(const float4*)(feat + (long)iid[j]*FDIM + c0);
    float4 acc = make_float4(0,0,0,0);
    #pragma unroll
    for(int j=0;j<10;j++) add4(acc, v[j]);
    so = make_float4(acc.x*0.1f, acc.y*0.1f, acc.z*0.1f, acc.w*0.1f);
    acc = make_float4(0,0,0,0);
    #pragma unroll
    for(int j=0;j<10;j++) add4(acc, v[10+j]);
    si = make_float4(acc.x*0.1f, acc.y*0.1f, acc.z*0.1f, acc.w*0.1f);
  }

  float* ar = agg + (long)row_local*KDIM;
  *(float4*)(ar + c0)       = selfv;
  *(float4*)(ar + 128 + c0) = so;
  *(float4*)(ar + 256 + c0) = si;
}

// Blocked GEMM + sigmoid: 64 rows/block (408 blocks), thread = 4 rows x 8 cols.
// W staged in LDS in 4 chunks of 96 k.
__global__ __launch_bounds__(256) void gemm_sig_kernel(
    const float* __restrict__ A, const float* __restrict__ W,
    float* __restrict__ out)
{
  __shared__ float Wbuf[96*128];       // 48 KB
  int t = threadIdx.x, lane = t&15, rg = t>>4;
  int r0 = blockIdx.x*64 + rg*4;
  int c0 = lane*8;
  float acc[4][8];
  #pragma unroll
  for(int r=0;r<4;r++)
    #pragma unroll
    for(int i=0;i<8;i++) acc[r][i]=0.f;

  for(int kc=0; kc<4; kc++){
    __syncthreads();
    const float4* ws = (const float4*)(W + kc*96*128);
    float4* wd = (float4*)Wbuf;
    #pragma unroll
    for(int i=0;i<12;i++) wd[i*256+t] = ws[i*256+t];
    __syncthreads();
    const float* Ab = A + (long)r0*KDIM + kc*96;
    #pragma unroll 2
    for(int k4=0;k4<96;k4+=4){
      float4 a0 = *(const float4*)(Ab + 0*KDIM + k4);
      float4 a1 = *(const float4*)(Ab + 1*KDIM + k4);
      float4 a2 = *(const float4*)(Ab + 2*KDIM + k4);
      float4 a3 = *(const float4*)(Ab + 3*KDIM + k4);
      #pragma unroll
      for(int kk=0;kk<4;kk++){
        float av0=getc(a0,kk), av1=getc(a1,kk), av2=getc(a2,kk), av3=getc(a3,kk);
        const float* wr = Wbuf + (k4+kk)*128 + c0;
        float4 w0 = *(const float4*)wr;
        float4 w1 = *(const float4*)(wr+4);
        acc[0][0]+=av0*w0.x; acc[0][1]+=av0*w0.y; acc[0][2]+=av0*w0.z; acc[0][3]+=av0*w0.w;
        acc[0][4]+=av0*w1.x; acc[0][5]+=av0*w1.y; acc[0][6]+=av0*w1.z; acc[0][7]+=av0*w1.w;
        acc[1][0]+=av1*w0.x; acc[1][1]+=av1*w0.y; acc[1][2]+=av1*w0.z; acc[1][3]+=av1*w0.w;
        acc[1][4]+=av1*w1.x; acc[1][5]+=av1*w1.y; acc[1][6]+=av1*w1.z; acc[1][7]+=av1*w1.w;
        acc[2][0]+=av2*w0.x; acc[2][1]+=av2*w0.y; acc[2][2]+=av2*w0.z; acc[2][3]+=av2*w0.w;
        acc[2][4]+=av2*w1.x; acc[2][5]+=av2*w1.y; acc[2][6]+=av2*w1.z; acc[2][7]+=av2*w1.w;
        acc[3][0]+=av3*w0.x; acc[3][1]+=av3*w0.y; acc[3][2]+=av3*w0.z; acc[3][3]+=av3*w0.w;
        acc[3][4]+=av3*w1.x; acc[3][5]+=av3*w1.y; acc[3][6]+=av3*w1.z; acc[3][7]+=av3*w1.w;
      }
    }
  }
  #pragma unroll
  for(int r=0;r<4;r++){
    float4 o0, o1;
    o0.x=sigf(acc[r][0]); o0.y=sigf(acc[r][1]); o0.z=sigf(acc[r][2]); o0.w=sigf(acc[r][3]);
    o1.x=sigf(acc[r][4]); o1.y=sigf(acc[r][5]); o1.z=sigf(acc[r][6]); o1.w=sigf(acc[r][7]);
    float* op = out + (long)(r0+r)*FDIM + c0;
    *(float4*)op = o0; *(float4*)(op+4) = o1;
  }
}

// Fused layer-1 agg + head GEMM + sigmoid + 128->64 projection.
// grid 384 = 3 heads x 128 row-quads; agg computed inline from L2-resident h.
// Block: 4 rows. Thread t: row = t>>6, lane = t&63.
__global__ __launch_bounds__(256) void head_kernel(
    const float* __restrict__ h,        // [26112][128]: rows 0..511 = h0, 512.. = h1
    const float* __restrict__ Wm, const float* __restrict__ Ws, const float* __restrict__ Wp,
    const float* __restrict__ Dm, const float* __restrict__ Ds, const float* __restrict__ Dp,
    float* __restrict__ out)            // [6][256][64]
{
  __shared__ float As[4*KDIM];          // 6 KB
  __shared__ float Hs[4*FDIM];          // 2 KB
  int head = blockIdx.x >> 7;           // 0..2
  int rt   = blockIdx.x & 127;          // 0..127
  int t = threadIdx.x;
  int row = t >> 6;                     // 0..3 (local)
  int lane = t & 63;
  const float* W = (head==0) ? Wm : (head==1) ? Ws : Wp;
  const float* D = (head==0) ? Dm : (head==1) ? Ds : Dp;
  int grow = rt*4 + row;                // 0..511

  // phase 1: inline aggregation. Each thread covers 2 channels (float2).
  {
    int c2 = lane*2;
    float2 selfv = *(const float2*)(h + (long)grow*FDIM + c2);
    const float* nb = h + (long)(512 + grow*50)*FDIM + c2;
    float2 s = make_float2(0,0);
    #pragma unroll
    for(int jj=0;jj<25;jj+=5){
      float2 v[5];
      #pragma unroll
      for(int i=0;i<5;i++) v[i] = *(const float2*)(nb + (long)(jj+i)*FDIM);
      #pragma unroll
      for(int i=0;i<5;i++) add2(s, v[i]);
    }
    float2 so = make_float2(s.x/25.f, s.y/25.f);
    s = make_float2(0,0);
    #pragma unroll
    for(int jj=25;jj<50;jj+=5){
      float2 v[5];
      #pragma unroll
      for(int i=0;i<5;i++) v[i] = *(const float2*)(nb + (long)(jj+i)*FDIM);
      #pragma unroll
      for(int i=0;i<5;i++) add2(s, v[i]);
    }
    float2 si = make_float2(s.x/25.f, s.y/25.f);
    *(float2*)&As[row*KDIM + c2]       = selfv;
    *(float2*)&As[row*KDIM + 128 + c2] = so;
    *(float2*)&As[row*KDIM + 256 + c2] = si;
  }
  __syncthreads();

  // phase 2: GEMM 384->128 + sigmoid. 2 cols per thread; wave reads W[k] 512 B contiguous.
  {
    int c = lane*2;
    float acc0 = 0.f, acc1 = 0.f;
    const float* as = As + row*KDIM;
    #pragma unroll 8
    for(int k=0;k<KDIM;k++){
      float a = as[k];
      float2 w = *(const float2*)(W + (long)k*FDIM + c);
      acc0 += a*w.x; acc1 += a*w.y;
    }
    Hs[row*FDIM + c]   = sigf(acc0);
    Hs[row*FDIM + c+1] = sigf(acc1);
  }
  __syncthreads();

  // phase 3: projection 128->64, one output per thread.
  {
    int col = lane;                     // 0..63
    const float* hs = Hs + row*FDIM;
    float a = 0.f;
    #pragma unroll 8
    for(int k=0;k<FDIM;k++){
      a += hs[k] * D[(long)k*64 + col];
    }
    int side = grow >> 8, b = grow & 255;
    out[((long)(side*3+head)*256 + b)*64 + col] = a;
  }
}

// ---------------- launch ----------------
extern "C" void kernel_launch(void* const* d_in, const int* in_sizes, int n_in,
                              void* d_out, int out_size, void* d_ws, size_t ws_size,
                              hipStream_t stream) {
  const int*   nodes1  = (const int*)d_in[0];
  const int*   nodes2  = (const int*)d_in[1];
  const int*   nout    = (const int*)d_in[2];
  const int*   nin     = (const int*)d_in[3];
  const float* feat    = (const float*)d_in[4];
  const float* W_in    = (const float*)d_in[5];
  const float* W_mean  = (const float*)d_in[6];
  const float* W_std   = (const float*)d_in[7];
  const float* W_pi    = (const float*)d_in[8];
  const float* Wd_mean = (const float*)d_in[11];
  const float* Wd_std  = (const float*)d_in[12];
  const float* Wd_pi   = (const float*)d_in[13];
  float* out = (float*)d_out;

  // workspace: h[26112][128] | aggChunk
  float* h    = (float*)d_ws;                          // 26112*128
  float* aggC = h + (size_t)NROWS*FDIM;

  // chunk count: smallest that fits ws (constant per session -> graph-safe).
  // chunkRows divisible by 64 (gemm) and 8 (gather).
  size_t fixedB = (size_t)NROWS*FDIM*4;
  const int ncOpt[5] = {1,2,4,12,51};
  int nc = 51;
  for(int i=0;i<5;i++){
    size_t need = fixedB + ((size_t)NROWS/ncOpt[i])*KDIM*4;
    if(need <= ws_size){ nc = ncOpt[i]; break; }
  }
  int chunkRows = NROWS / nc;

  ColsBoth cb;
  compute_cols(cb);

  for(int c=0;c<nc;c++){
    int base = c*chunkRows;
    gather_kernel<<<chunkRows/8, 256, 0, stream>>>(feat, nodes1, nodes2,
                                                   nout, nin, aggC, base, cb);
    gemm_sig_kernel<<<chunkRows/64, 256, 0, stream>>>(aggC, W_in, h + (size_t)base*FDIM);
  }
  head_kernel<<<384, 256, 0, stream>>>(h, W_mean, W_std, W_pi, Wd_mean, Wd_std, Wd_pi, out);
}